// Round 8
// baseline (250.853 us; speedup 1.0000x reference)
//
#include <hip/hip_runtime.h>

// InitReduceConv: out[dst[e], :] += x[src[e], :]  (E=2M edges, D=64 fp32)
//
// Pipeline: memset(cursor) -> XCD-partitioned bucket build -> XCD-partitioned
//           gather-sum -> overflow fixup (statistically empty).
//
// Round-7 change: cache-hint discipline. Index streams are read-once ->
// __builtin_nontemporal_load (early eviction), so bucket lines survive in
// the XCD-private L2 until all ~20 writes/row combine (round-6 showed the
// streaming fetch thrashing them out: WRITE_SIZE 96 MB vs ~13 MB floor).
// Gather: bucket entries nt-loaded (read once), out nt-stored (written
// once), keeping L2/L3 for the 20x-reused x rows.
//
// ws layout: [0, NOUT*4)            cursor (N_OUT ints)
//            [NOUT*4, +8)           ovf count
//            [NOUT*4+8, ...)        ovf (src,dst) pairs
//            [1M, 1M+25.6M)         bucket (N_OUT * 64 ints)

#define CAP 64
#define OVF_CAP 32768
#define BUCKET_OFF (1024u * 1024u)
#define EDGES_PER_THREAD 8

typedef int   vi4 __attribute__((ext_vector_type(4)));
typedef float vf4 __attribute__((ext_vector_type(4)));

__global__ void bucket_xcd_kernel(const int* __restrict__ bidx,
                                  int* __restrict__ cursor,
                                  int* __restrict__ bucket,
                                  int* __restrict__ ovf,
                                  int E) {
    const int part = blockIdx.x & 7;
    const int chunk = blockIdx.x >> 3;
    int e0 = (chunk * blockDim.x + threadIdx.x) * EDGES_PER_THREAD;
    if (e0 >= E) return;

    if (e0 + EDGES_PER_THREAD <= E) {
        // dst quads first (nontemporal: read-once stream, don't pollute L2)
        vi4 d0 = __builtin_nontemporal_load((const vi4*)(bidx + E + e0));
        vi4 d1 = __builtin_nontemporal_load((const vi4*)(bidx + E + e0 + 4));

        bool m0 = ((d0.x & 7) == part) | ((d0.y & 7) == part) |
                  ((d0.z & 7) == part) | ((d0.w & 7) == part);
        if (m0) {
            vi4 s0 = __builtin_nontemporal_load((const vi4*)(bidx + e0));
            int ss[4] = {s0.x, s0.y, s0.z, s0.w};
            int dd[4] = {d0.x, d0.y, d0.z, d0.w};
#pragma unroll
            for (int k = 0; k < 4; ++k) {
                int dst = dd[k];
                if ((dst & 7) != part) continue;
                int pos = atomicAdd(&cursor[dst], 1);
                if (pos < CAP) {
                    bucket[dst * CAP + pos] = ss[k];
                } else {
                    int p = atomicAdd(&ovf[0], 1);
                    if (p < OVF_CAP) { ovf[1 + 2 * p] = ss[k]; ovf[2 + 2 * p] = dst; }
                }
            }
        }
        bool m1 = ((d1.x & 7) == part) | ((d1.y & 7) == part) |
                  ((d1.z & 7) == part) | ((d1.w & 7) == part);
        if (m1) {
            vi4 s1 = __builtin_nontemporal_load((const vi4*)(bidx + e0 + 4));
            int ss[4] = {s1.x, s1.y, s1.z, s1.w};
            int dd[4] = {d1.x, d1.y, d1.z, d1.w};
#pragma unroll
            for (int k = 0; k < 4; ++k) {
                int dst = dd[k];
                if ((dst & 7) != part) continue;
                int pos = atomicAdd(&cursor[dst], 1);
                if (pos < CAP) {
                    bucket[dst * CAP + pos] = ss[k];
                } else {
                    int p = atomicAdd(&ovf[0], 1);
                    if (p < OVF_CAP) { ovf[1 + 2 * p] = ss[k]; ovf[2 + 2 * p] = dst; }
                }
            }
        }
    } else {
        for (int e = e0; e < E; ++e) {
            int dst = bidx[E + e];
            if ((dst & 7) != part) continue;
            int src = bidx[e];
            int pos = atomicAdd(&cursor[dst], 1);
            if (pos < CAP) {
                bucket[dst * CAP + pos] = src;
            } else {
                int p = atomicAdd(&ovf[0], 1);
                if (p < OVF_CAP) { ovf[1 + 2 * p] = src; ovf[2 + 2 * p] = dst; }
            }
        }
    }
}

// 16 threads per output row, one float4 each; rows of class p handled by
// blocks with (blockIdx&7)==p so bucket lines are read on the XCD that
// wrote them. Bucket entries nt-loaded (read once); out nt-stored (written
// once) -> L2/L3 stays reserved for the 20x-reused x rows.
__global__ void gather_xcd_kernel(const float4* __restrict__ x4,
                                  const int* __restrict__ cursor,
                                  const int* __restrict__ bucket,
                                  float* __restrict__ out,
                                  int NOUT) {
    const int part = blockIdx.x & 7;
    const int i = blockIdx.x >> 3;
    int t = i * blockDim.x + threadIdx.x;
    int lrow = t >> 4;
    int c = t & 15;
    int row = part + (lrow << 3);
    if (row >= NOUT) return;

    int deg = cursor[row];
    if (deg > CAP) deg = CAP;
    const int* __restrict__ b = bucket + row * CAP;

    float4 acc0 = {0.f, 0.f, 0.f, 0.f};
    float4 acc1 = {0.f, 0.f, 0.f, 0.f};
    int nfull = deg >> 2;
    for (int j4 = 0; j4 < nfull; ++j4) {
        vi4 s = __builtin_nontemporal_load((const vi4*)(b + (j4 << 2)));
        float4 v0 = x4[(size_t)s.x * 16 + c];
        float4 v1 = x4[(size_t)s.y * 16 + c];
        float4 v2 = x4[(size_t)s.z * 16 + c];
        float4 v3 = x4[(size_t)s.w * 16 + c];
        acc0.x += v0.x + v1.x; acc0.y += v0.y + v1.y;
        acc0.z += v0.z + v1.z; acc0.w += v0.w + v1.w;
        acc1.x += v2.x + v3.x; acc1.y += v2.y + v3.y;
        acc1.z += v2.z + v3.z; acc1.w += v2.w + v3.w;
    }
    for (int j = nfull << 2; j < deg; ++j) {
        int src = b[j];
        float4 v = x4[(size_t)src * 16 + c];
        acc0.x += v.x; acc0.y += v.y; acc0.z += v.z; acc0.w += v.w;
    }
    vf4 r;
    r.x = acc0.x + acc1.x; r.y = acc0.y + acc1.y;
    r.z = acc0.z + acc1.z; r.w = acc0.w + acc1.w;
    __builtin_nontemporal_store(r, (vf4*)(out + (size_t)row * 64 + (c << 2)));
}

__global__ void overflow_kernel(const float* __restrict__ x,
                                const int* __restrict__ ovf,
                                float* __restrict__ out) {
    int n = ovf[0];
    if (n > OVF_CAP) n = OVF_CAP;
    for (int i = blockIdx.x; i < n; i += gridDim.x) {
        int src = ovf[1 + 2 * i];
        int dst = ovf[2 + 2 * i];
        atomicAdd(&out[(size_t)dst * 64 + threadIdx.x],
                  x[(size_t)src * 64 + threadIdx.x]);
    }
}

// Fallbacks for unexpected shapes.
__global__ void bucket_kernel1(const int* __restrict__ bidx,
                               int* __restrict__ cursor,
                               int* __restrict__ bucket,
                               int* __restrict__ ovf,
                               int E) {
    int e = blockIdx.x * blockDim.x + threadIdx.x;
    if (e >= E) return;
    int src = bidx[e];
    int dst = bidx[E + e];
    int pos = atomicAdd(&cursor[dst], 1);
    if (pos < CAP) bucket[dst * CAP + pos] = src;
    else { int p = atomicAdd(&ovf[0], 1); if (p < OVF_CAP) { ovf[1+2*p] = src; ovf[2+2*p] = dst; } }
}

__global__ void scatter_add_f4_kernel(const float4* __restrict__ x4,
                                      const int* __restrict__ bidx,
                                      float* __restrict__ out,
                                      int E) {
    int idx = blockIdx.x * blockDim.x + threadIdx.x;
    int total = E * 16;
    if (idx >= total) return;
    int e = idx >> 4;
    int c = idx & 15;
    int src = bidx[e];
    int dst = bidx[E + e];
    float4 v = x4[(size_t)src * 16 + c];
    float* o = out + (size_t)dst * 64 + (c << 2);
    atomicAdd(o + 0, v.x);
    atomicAdd(o + 1, v.y);
    atomicAdd(o + 2, v.z);
    atomicAdd(o + 3, v.w);
}

extern "C" void kernel_launch(void* const* d_in, const int* in_sizes, int n_in,
                              void* d_out, int out_size, void* d_ws, size_t ws_size,
                              hipStream_t stream) {
    const float* x = (const float*)d_in[0];
    const int* bidx = (const int*)d_in[1];
    float* out = (float*)d_out;

    const int E = in_sizes[1] / 2;     // 2,000,000
    const int NOUT = out_size / 64;    // 100,000

    size_t needed = (size_t)BUCKET_OFF + (size_t)NOUT * CAP * sizeof(int);
    if (ws_size < needed) {
        hipMemsetAsync(d_out, 0, (size_t)out_size * sizeof(float), stream);
        int total = E * 16;
        scatter_add_f4_kernel<<<(total + 255) / 256, 256, 0, stream>>>(
            (const float4*)x, bidx, out, E);
        return;
    }

    char* ws = (char*)d_ws;
    int* cursor = (int*)ws;
    int* ovf = (int*)(ws + (size_t)NOUT * sizeof(int));
    int* bucket = (int*)(ws + BUCKET_OFF);

    // Zero cursor + overflow count only.
    hipMemsetAsync(ws, 0, (size_t)NOUT * sizeof(int) + 2 * sizeof(int), stream);

    if ((E & 7) == 0) {
        // 8 partition-blocks per chunk of 256*8 edges.
        int nchunks = (E / EDGES_PER_THREAD + 255) / 256;
        bucket_xcd_kernel<<<nchunks * 8, 256, 0, stream>>>(bidx, cursor, bucket, ovf, E);
    } else {
        bucket_kernel1<<<(E + 255) / 256, 256, 0, stream>>>(bidx, cursor, bucket, ovf, E);
    }

    // Gather: rows per partition, 16 rows per 256-thread block.
    int rows_per_part = (NOUT + 7) / 8;
    int blocks_per_part = (rows_per_part * 16 + 255) / 256;
    gather_xcd_kernel<<<blocks_per_part * 8, 256, 0, stream>>>(
        (const float4*)x, cursor, bucket, out, NOUT);

    overflow_kernel<<<64, 64, 0, stream>>>(x, ovf, out);
}

// Round 9
// 244.000 us; speedup vs baseline: 1.0281x; 1.0281x over previous
//
#include <hip/hip_runtime.h>

// InitReduceConv: out[dst[e], :] += x[src[e], :]  (E=2M edges, D=64 fp32)
//
// Pipeline: memset(cursor) -> XCD-partitioned bucket build -> shuffle-bcast
//           gather-sum -> overflow fixup (statistically empty).
//
// Round-9 change: gather de-serialization. Old gather: 5 serialized
// {int4 load -> 4 gathers} iterations per row. New: the row's 64 bucket
// slots are loaded with ONE coalesced int4/lane (16 lanes = 256 B), then
// __shfl broadcasts entry j from its owning lane -- all ~20 x-row gathers
// are independent, in flight together (L3-throughput-bound, not
// latency-chain-bound).
// Bucket build unchanged from round 8 (LDS multi-split is the next move:
// NT hints proved unable to stop L2 thrash of bucket lines).
//
// ws layout: [0, NOUT*4)            cursor (N_OUT ints)
//            [NOUT*4, +8)           ovf count
//            [NOUT*4+8, ...)        ovf (src,dst) pairs
//            [1M, 1M+25.6M)         bucket (N_OUT * 64 ints)

#define CAP 64
#define OVF_CAP 32768
#define BUCKET_OFF (1024u * 1024u)
#define EDGES_PER_THREAD 8

typedef int   vi4 __attribute__((ext_vector_type(4)));
typedef float vf4 __attribute__((ext_vector_type(4)));

__global__ void bucket_xcd_kernel(const int* __restrict__ bidx,
                                  int* __restrict__ cursor,
                                  int* __restrict__ bucket,
                                  int* __restrict__ ovf,
                                  int E) {
    const int part = blockIdx.x & 7;
    const int chunk = blockIdx.x >> 3;
    int e0 = (chunk * blockDim.x + threadIdx.x) * EDGES_PER_THREAD;
    if (e0 >= E) return;

    if (e0 + EDGES_PER_THREAD <= E) {
        vi4 d0 = __builtin_nontemporal_load((const vi4*)(bidx + E + e0));
        vi4 d1 = __builtin_nontemporal_load((const vi4*)(bidx + E + e0 + 4));

        bool m0 = ((d0.x & 7) == part) | ((d0.y & 7) == part) |
                  ((d0.z & 7) == part) | ((d0.w & 7) == part);
        if (m0) {
            vi4 s0 = __builtin_nontemporal_load((const vi4*)(bidx + e0));
            int ss[4] = {s0.x, s0.y, s0.z, s0.w};
            int dd[4] = {d0.x, d0.y, d0.z, d0.w};
#pragma unroll
            for (int k = 0; k < 4; ++k) {
                int dst = dd[k];
                if ((dst & 7) != part) continue;
                int pos = atomicAdd(&cursor[dst], 1);
                if (pos < CAP) {
                    bucket[dst * CAP + pos] = ss[k];
                } else {
                    int p = atomicAdd(&ovf[0], 1);
                    if (p < OVF_CAP) { ovf[1 + 2 * p] = ss[k]; ovf[2 + 2 * p] = dst; }
                }
            }
        }
        bool m1 = ((d1.x & 7) == part) | ((d1.y & 7) == part) |
                  ((d1.z & 7) == part) | ((d1.w & 7) == part);
        if (m1) {
            vi4 s1 = __builtin_nontemporal_load((const vi4*)(bidx + e0 + 4));
            int ss[4] = {s1.x, s1.y, s1.z, s1.w};
            int dd[4] = {d1.x, d1.y, d1.z, d1.w};
#pragma unroll
            for (int k = 0; k < 4; ++k) {
                int dst = dd[k];
                if ((dst & 7) != part) continue;
                int pos = atomicAdd(&cursor[dst], 1);
                if (pos < CAP) {
                    bucket[dst * CAP + pos] = ss[k];
                } else {
                    int p = atomicAdd(&ovf[0], 1);
                    if (p < OVF_CAP) { ovf[1 + 2 * p] = ss[k]; ovf[2 + 2 * p] = dst; }
                }
            }
        }
    } else {
        for (int e = e0; e < E; ++e) {
            int dst = bidx[E + e];
            if ((dst & 7) != part) continue;
            int src = bidx[e];
            int pos = atomicAdd(&cursor[dst], 1);
            if (pos < CAP) {
                bucket[dst * CAP + pos] = src;
            } else {
                int p = atomicAdd(&ovf[0], 1);
                if (p < OVF_CAP) { ovf[1 + 2 * p] = src; ovf[2 + 2 * p] = dst; }
            }
        }
    }
}

// 16 lanes per output row. One coalesced int4/lane covers all 64 bucket
// slots of the row; __shfl broadcasts entry j from lane (grpBase | j>>2).
// All deg gathers are independent -> deep MLP instead of a serial chain.
__global__ void gather_shfl_kernel(const float4* __restrict__ x4,
                                   const int* __restrict__ cursor,
                                   const int* __restrict__ bucket,
                                   float* __restrict__ out,
                                   int NOUT) {
    const int part = blockIdx.x & 7;
    const int i = blockIdx.x >> 3;
    int t = i * blockDim.x + threadIdx.x;
    int lrow = t >> 4;
    int c = t & 15;
    int row = part + (lrow << 3);
    if (row >= NOUT) return;

    int deg = cursor[row];
    if (deg > CAP) deg = CAP;

    // lanes 0..15 of the group read the row's 64 slots, coalesced (256 B)
    const int4* __restrict__ b4 = (const int4*)(bucket + (size_t)row * CAP);
    int4 mine = b4[c];

    const int lane = threadIdx.x & 63;
    const int grpBase = lane & 48;   // 4 groups of 16 lanes per wave

    float4 a0 = {0.f, 0.f, 0.f, 0.f};
    float4 a1 = {0.f, 0.f, 0.f, 0.f};
    float4 a2 = {0.f, 0.f, 0.f, 0.f};
    float4 a3 = {0.f, 0.f, 0.f, 0.f};

#pragma unroll 2
    for (int j = 0; j < deg; j += 4) {
        int sl = grpBase | (j >> 2);       // lane holding entries j..j+3
        int s0 = __shfl(mine.x, sl, 64);
        int s1 = __shfl(mine.y, sl, 64);
        int s2 = __shfl(mine.z, sl, 64);
        int s3 = __shfl(mine.w, sl, 64);
        {
            float4 v = x4[(size_t)s0 * 16 + c];
            a0.x += v.x; a0.y += v.y; a0.z += v.z; a0.w += v.w;
        }
        if (j + 1 < deg) {
            float4 v = x4[(size_t)s1 * 16 + c];
            a1.x += v.x; a1.y += v.y; a1.z += v.z; a1.w += v.w;
        }
        if (j + 2 < deg) {
            float4 v = x4[(size_t)s2 * 16 + c];
            a2.x += v.x; a2.y += v.y; a2.z += v.z; a2.w += v.w;
        }
        if (j + 3 < deg) {
            float4 v = x4[(size_t)s3 * 16 + c];
            a3.x += v.x; a3.y += v.y; a3.z += v.z; a3.w += v.w;
        }
    }
    vf4 r;
    r.x = (a0.x + a1.x) + (a2.x + a3.x);
    r.y = (a0.y + a1.y) + (a2.y + a3.y);
    r.z = (a0.z + a1.z) + (a2.z + a3.z);
    r.w = (a0.w + a1.w) + (a2.w + a3.w);
    __builtin_nontemporal_store(r, (vf4*)(out + (size_t)row * 64 + (c << 2)));
}

__global__ void overflow_kernel(const float* __restrict__ x,
                                const int* __restrict__ ovf,
                                float* __restrict__ out) {
    int n = ovf[0];
    if (n > OVF_CAP) n = OVF_CAP;
    for (int i = blockIdx.x; i < n; i += gridDim.x) {
        int src = ovf[1 + 2 * i];
        int dst = ovf[2 + 2 * i];
        atomicAdd(&out[(size_t)dst * 64 + threadIdx.x],
                  x[(size_t)src * 64 + threadIdx.x]);
    }
}

// Fallbacks for unexpected shapes.
__global__ void bucket_kernel1(const int* __restrict__ bidx,
                               int* __restrict__ cursor,
                               int* __restrict__ bucket,
                               int* __restrict__ ovf,
                               int E) {
    int e = blockIdx.x * blockDim.x + threadIdx.x;
    if (e >= E) return;
    int src = bidx[e];
    int dst = bidx[E + e];
    int pos = atomicAdd(&cursor[dst], 1);
    if (pos < CAP) bucket[dst * CAP + pos] = src;
    else { int p = atomicAdd(&ovf[0], 1); if (p < OVF_CAP) { ovf[1+2*p] = src; ovf[2+2*p] = dst; } }
}

__global__ void scatter_add_f4_kernel(const float4* __restrict__ x4,
                                      const int* __restrict__ bidx,
                                      float* __restrict__ out,
                                      int E) {
    int idx = blockIdx.x * blockDim.x + threadIdx.x;
    int total = E * 16;
    if (idx >= total) return;
    int e = idx >> 4;
    int c = idx & 15;
    int src = bidx[e];
    int dst = bidx[E + e];
    float4 v = x4[(size_t)src * 16 + c];
    float* o = out + (size_t)dst * 64 + (c << 2);
    atomicAdd(o + 0, v.x);
    atomicAdd(o + 1, v.y);
    atomicAdd(o + 2, v.z);
    atomicAdd(o + 3, v.w);
}

extern "C" void kernel_launch(void* const* d_in, const int* in_sizes, int n_in,
                              void* d_out, int out_size, void* d_ws, size_t ws_size,
                              hipStream_t stream) {
    const float* x = (const float*)d_in[0];
    const int* bidx = (const int*)d_in[1];
    float* out = (float*)d_out;

    const int E = in_sizes[1] / 2;     // 2,000,000
    const int NOUT = out_size / 64;    // 100,000

    size_t needed = (size_t)BUCKET_OFF + (size_t)NOUT * CAP * sizeof(int);
    if (ws_size < needed) {
        hipMemsetAsync(d_out, 0, (size_t)out_size * sizeof(float), stream);
        int total = E * 16;
        scatter_add_f4_kernel<<<(total + 255) / 256, 256, 0, stream>>>(
            (const float4*)x, bidx, out, E);
        return;
    }

    char* ws = (char*)d_ws;
    int* cursor = (int*)ws;
    int* ovf = (int*)(ws + (size_t)NOUT * sizeof(int));
    int* bucket = (int*)(ws + BUCKET_OFF);

    // Zero cursor + overflow count only.
    hipMemsetAsync(ws, 0, (size_t)NOUT * sizeof(int) + 2 * sizeof(int), stream);

    if ((E & 7) == 0) {
        int nchunks = (E / EDGES_PER_THREAD + 255) / 256;
        bucket_xcd_kernel<<<nchunks * 8, 256, 0, stream>>>(bidx, cursor, bucket, ovf, E);
    } else {
        bucket_kernel1<<<(E + 255) / 256, 256, 0, stream>>>(bidx, cursor, bucket, ovf, E);
    }

    // Gather: rows per partition, 16 rows per 256-thread block.
    int rows_per_part = (NOUT + 7) / 8;
    int blocks_per_part = (rows_per_part * 16 + 255) / 256;
    gather_shfl_kernel<<<blocks_per_part * 8, 256, 0, stream>>>(
        (const float4*)x, cursor, bucket, out, NOUT);

    overflow_kernel<<<64, 64, 0, stream>>>(x, ovf, out);
}